// Round 2
// baseline (269.420 us; speedup 1.0000x reference)
//
#include <hip/hip_runtime.h>

#define HH 256
#define WW 256
#define BB 4
#define HW (HH*WW)
#define N_ITER 20
#define EPSV 1e-8f

#define FUSE 2
#define TILE 32
#define HALO (2*FUSE)            // 4
#define EXT  (TILE + 2*HALO)     // 40
#define EPAD (EXT + 1)           // 41, pad to avoid bank conflicts
#define MAXPX 6                  // ceil(38*38 / 256)

__device__ __forceinline__ float ldz(const float* __restrict__ p, int y, int x) {
    if ((unsigned)y < HH && (unsigned)x < WW) return p[y*WW + x];
    return 0.0f;
}
__device__ __forceinline__ float sobelXg(const float* __restrict__ p, int y, int x) {
    return -ldz(p,y-1,x-1) + ldz(p,y-1,x+1)
         - 2.0f*ldz(p,y,x-1) + 2.0f*ldz(p,y,x+1)
         - ldz(p,y+1,x-1) + ldz(p,y+1,x+1);
}
__device__ __forceinline__ float sobelYg(const float* __restrict__ p, int y, int x) {
    return -ldz(p,y-1,x-1) - 2.0f*ldz(p,y-1,x) - ldz(p,y-1,x+1)
          + ldz(p,y+1,x-1) + 2.0f*ldz(p,y+1,x) + ldz(p,y+1,x+1);
}

// LDS sobel (cross-correlation), indices guaranteed in-bounds of ext tile
#define SBX(s,y,x) (-s[(y)-1][(x)-1] + s[(y)-1][(x)+1] \
                    - 2.0f*s[(y)][(x)-1] + 2.0f*s[(y)][(x)+1] \
                    - s[(y)+1][(x)-1] + s[(y)+1][(x)+1])
#define SBY(s,y,x) (-s[(y)-1][(x)-1] - 2.0f*s[(y)-1][(x)] - s[(y)-1][(x)+1] \
                    + s[(y)+1][(x)-1] + 2.0f*s[(y)+1][(x)] + s[(y)+1][(x)+1])

__global__ void tvl1_init(const float* __restrict__ xin, float* __restrict__ u,
                          float* __restrict__ p1, float* __restrict__ p2,
                          float* __restrict__ gx, float* __restrict__ gy,
                          float* __restrict__ rc) {
    int x = blockIdx.x*blockDim.x + threadIdx.x;
    int y = blockIdx.y*blockDim.y + threadIdx.y;
    int b = blockIdx.z;
    int idx = y*WW + x;
    int pb = b*2*HW;
    const float* im1 = xin + pb + HW;     // channel 1
    float i1 = im1[idx];
    rc[b*HW + idx] = i1 - xin[pb + idx];  // im1 - im0
    gx[b*HW + idx] = sobelXg(im1, y, x);
    gy[b*HW + idx] = sobelYg(im1, y, x);
    u[pb + idx] = 0.0f;  u[pb + HW + idx] = 0.0f;
    p1[pb + idx] = 0.0f; p1[pb + HW + idx] = 0.0f;
    p2[pb + idx] = 0.0f; p2[pb + HW + idx] = 0.0f;
}

template<int LAST>
__global__ __launch_bounds__(256)
void tvl1_fused(float* __restrict__ u,
                float* __restrict__ p1, float* __restrict__ p2,
                const float* __restrict__ gx, const float* __restrict__ gy,
                const float* __restrict__ rc,
                const float* __restrict__ lam, const float* __restrict__ tau,
                const float* __restrict__ the) {
    __shared__ float su0[EXT][EPAD], su1[EXT][EPAD];
    __shared__ float sp10[EXT][EPAD], sp11[EXT][EPAD];
    __shared__ float sp20[EXT][EPAD], sp21[EXT][EPAD];
    __shared__ float sgx[EXT][EPAD], sgy[EXT][EPAD], src_[EXT][EPAD];

    const int tid = threadIdx.x;
    const int b = blockIdx.z;
    const int ox = blockIdx.x*TILE - HALO;
    const int oy = blockIdx.y*TILE - HALO;
    const int pb = b*2*HW, cb = b*HW;
    const float theta = the[0];
    const float tl = theta * lam[0];
    const float r = tau[0] / theta;

    // ---- stage extended tile (zeros outside image) ----
    for (int i = tid; i < EXT*EXT; i += 256) {
        int ly = i / EXT, lx = i - ly*EXT;
        int gyy = oy + ly, gxx = ox + lx;
        bool in = ((unsigned)gyy < HH) && ((unsigned)gxx < WW);
        int gi = gyy*WW + gxx;
        su0[ly][lx]  = in ? u[pb + gi]       : 0.0f;
        su1[ly][lx]  = in ? u[pb + HW + gi]  : 0.0f;
        sp10[ly][lx] = in ? p1[pb + gi]      : 0.0f;
        sp11[ly][lx] = in ? p1[pb + HW + gi] : 0.0f;
        sp20[ly][lx] = in ? p2[pb + gi]      : 0.0f;
        sp21[ly][lx] = in ? p2[pb + HW + gi] : 0.0f;
        sgx[ly][lx]  = in ? gx[cb + gi]      : 0.0f;
        sgy[ly][lx]  = in ? gy[cb + gi]      : 0.0f;
        src_[ly][lx] = in ? rc[cb + gi]      : 0.0f;
    }
    __syncthreads();

    const int NH = LAST ? (2*FUSE - 1) : (2*FUSE);
    for (int h = 0; h < NH; ++h) {
        const int lo = h + 1, hi = EXT - 1 - h;
        const int w = hi - lo;
        const int n = w * w;
        if ((h & 1) == 0) {
            // ---- u half-step: reads old u (pointwise), p neighbors ----
            float nv0[MAXPX], nv1[MAXPX];
            #pragma unroll
            for (int k = 0; k < MAXPX; ++k) {
                int i = tid + k*256;
                if (i < n) {
                    int q = i / w;
                    int ly = lo + q, lx = lo + (i - q*w);
                    float g_x = sgx[ly][lx], g_y = sgy[ly][lx];
                    float ng  = g_x*g_x + g_y*g_y + EPSV;
                    float u0  = su0[ly][lx], u1v = su1[ly][lx];
                    float rho = src_[ly][lx] + g_x*u0 + g_y*u1v;
                    float th  = tl * ng;
                    float sgn = (rho > 0.0f) ? 1.0f : ((rho < 0.0f) ? -1.0f : 0.0f);
                    float d   = (fabsf(rho) < th) ? (rho / ng) : (tl * sgn);
                    float div0 = SBX(sp10, ly, lx) + SBY(sp20, ly, lx);
                    float div1 = SBX(sp11, ly, lx) + SBY(sp21, ly, lx);
                    bool in = ((unsigned)(oy+ly) < HH) && ((unsigned)(ox+lx) < WW);
                    nv0[k] = in ? (u0 - d*g_x + theta*div0) : 0.0f;
                    nv1[k] = in ? (u1v - d*g_y + theta*div1) : 0.0f;
                }
            }
            __syncthreads();
            #pragma unroll
            for (int k = 0; k < MAXPX; ++k) {
                int i = tid + k*256;
                if (i < n) {
                    int q = i / w;
                    int ly = lo + q, lx = lo + (i - q*w);
                    su0[ly][lx] = nv0[k];
                    su1[ly][lx] = nv1[k];
                }
            }
            __syncthreads();
        } else {
            // ---- p half-step: reads new u neighbors, old p (pointwise) ----
            float n10[MAXPX], n11[MAXPX], n20[MAXPX], n21[MAXPX];
            #pragma unroll
            for (int k = 0; k < MAXPX; ++k) {
                int i = tid + k*256;
                if (i < n) {
                    int q = i / w;
                    int ly = lo + q, lx = lo + (i - q*w);
                    float g1x = SBX(su0, ly, lx), g1y = SBY(su0, ly, lx);
                    float g2x = SBX(su1, ly, lx), g2y = SBY(su1, ly, lx);
                    float inv1 = 1.0f / (1.0f + r*(fabsf(g1x) + fabsf(g1y)));
                    float inv2 = 1.0f / (1.0f + r*(fabsf(g2x) + fabsf(g2y)));
                    bool in = ((unsigned)(oy+ly) < HH) && ((unsigned)(ox+lx) < WW);
                    n10[k] = in ? (sp10[ly][lx] + r*g1x) * inv1 : 0.0f;
                    n11[k] = in ? (sp11[ly][lx] + r*g1y) * inv1 : 0.0f;
                    n20[k] = in ? (sp20[ly][lx] + r*g2x) * inv2 : 0.0f;
                    n21[k] = in ? (sp21[ly][lx] + r*g2y) * inv2 : 0.0f;
                }
            }
            __syncthreads();
            #pragma unroll
            for (int k = 0; k < MAXPX; ++k) {
                int i = tid + k*256;
                if (i < n) {
                    int q = i / w;
                    int ly = lo + q, lx = lo + (i - q*w);
                    sp10[ly][lx] = n10[k];
                    sp11[ly][lx] = n11[k];
                    sp20[ly][lx] = n20[k];
                    sp21[ly][lx] = n21[k];
                }
            }
            __syncthreads();
        }
    }

    // ---- write back interior ----
    for (int i = tid; i < TILE*TILE; i += 256) {
        int ly = HALO + i / TILE, lx = HALO + (i % TILE);
        int gi = (oy + ly)*WW + (ox + lx);   // interior is always in-image
        u[pb + gi]      = su0[ly][lx];
        u[pb + HW + gi] = su1[ly][lx];
        if (!LAST) {
            p1[pb + gi]      = sp10[ly][lx];
            p1[pb + HW + gi] = sp11[ly][lx];
            p2[pb + gi]      = sp20[ly][lx];
            p2[pb + HW + gi] = sp21[ly][lx];
        }
    }
}

extern "C" void kernel_launch(void* const* d_in, const int* in_sizes, int n_in,
                              void* d_out, int out_size, void* d_ws, size_t ws_size,
                              hipStream_t stream) {
    const float* xin = (const float*)d_in[0];
    const float* lam = (const float*)d_in[1];
    const float* tau = (const float*)d_in[2];
    const float* the = (const float*)d_in[3];
    float* u = (float*)d_out;              // u lives in d_out (B,2,H,W)

    float* ws = (float*)d_ws;
    float* p1 = ws;                        // B*2*HW
    float* p2 = ws + (size_t)BB*2*HW;      // B*2*HW
    float* gx = ws + (size_t)2*BB*2*HW;    // B*HW
    float* gy = gx + (size_t)BB*HW;        // B*HW
    float* rc = gy + (size_t)BB*HW;        // B*HW

    {
        dim3 blk(64, 4, 1);
        dim3 grd(WW/64, HH/4, BB);
        tvl1_init<<<grd, blk, 0, stream>>>(xin, u, p1, p2, gx, gy, rc);
    }

    dim3 blk(256, 1, 1);
    dim3 grd(WW/TILE, HH/TILE, BB);        // 8 x 8 x 4 = 256 blocks
    const int NLAUNCH = N_ITER / FUSE;     // 10
    for (int j = 0; j < NLAUNCH; ++j) {
        if (j < NLAUNCH - 1)
            tvl1_fused<0><<<grd, blk, 0, stream>>>(u, p1, p2, gx, gy, rc, lam, tau, the);
        else
            tvl1_fused<1><<<grd, blk, 0, stream>>>(u, p1, p2, gx, gy, rc, lam, tau, the);
    }
}

// Round 3
// 110.815 us; speedup vs baseline: 2.4313x; 2.4313x over previous
//
#include <hip/hip_runtime.h>

#define HH 256
#define WW 256
#define BB 4
#define HW (HH*WW)
#define N_ITER 20
#define EPSV 1e-8f

#define FUSE 4
#define TILE 32
#define HALO (2*FUSE)            // 8
#define EXT  (TILE + 2*HALO)     // 48
#define EPAD (EXT + 1)           // 49
#define NTHR 1024
#define NPX  ((EXT*EXT + NTHR - 1) / NTHR)   // 3

__device__ __forceinline__ float ldz(const float* __restrict__ p, int y, int x) {
    if ((unsigned)y < HH && (unsigned)x < WW) return p[y*WW + x];
    return 0.0f;
}
__device__ __forceinline__ float sobelXg(const float* __restrict__ p, int y, int x) {
    return -ldz(p,y-1,x-1) + ldz(p,y-1,x+1)
         - 2.0f*ldz(p,y,x-1) + 2.0f*ldz(p,y,x+1)
         - ldz(p,y+1,x-1) + ldz(p,y+1,x+1);
}
__device__ __forceinline__ float sobelYg(const float* __restrict__ p, int y, int x) {
    return -ldz(p,y-1,x-1) - 2.0f*ldz(p,y-1,x) - ldz(p,y-1,x+1)
          + ldz(p,y+1,x-1) + 2.0f*ldz(p,y+1,x) + ldz(p,y+1,x+1);
}

#define SBX(s,y,x) (-s[(y)-1][(x)-1] + s[(y)-1][(x)+1] \
                    - 2.0f*s[(y)][(x)-1] + 2.0f*s[(y)][(x)+1] \
                    - s[(y)+1][(x)-1] + s[(y)+1][(x)+1])
#define SBY(s,y,x) (-s[(y)-1][(x)-1] - 2.0f*s[(y)-1][(x)] - s[(y)-1][(x)+1] \
                    + s[(y)+1][(x)-1] + 2.0f*s[(y)+1][(x)] + s[(y)+1][(x)+1])

__global__ void tvl1_init(const float* __restrict__ xin, float* __restrict__ u,
                          float* __restrict__ p1, float* __restrict__ p2,
                          float* __restrict__ gx, float* __restrict__ gy,
                          float* __restrict__ rc) {
    int x = blockIdx.x*blockDim.x + threadIdx.x;
    int y = blockIdx.y*blockDim.y + threadIdx.y;
    int b = blockIdx.z;
    int idx = y*WW + x;
    int pb = b*2*HW;
    const float* im1 = xin + pb + HW;     // channel 1
    float i1 = im1[idx];
    rc[b*HW + idx] = i1 - xin[pb + idx];  // im1 - im0
    gx[b*HW + idx] = sobelXg(im1, y, x);
    gy[b*HW + idx] = sobelYg(im1, y, x);
    u[pb + idx] = 0.0f;  u[pb + HW + idx] = 0.0f;
    p1[pb + idx] = 0.0f; p1[pb + HW + idx] = 0.0f;
    p2[pb + idx] = 0.0f; p2[pb + HW + idx] = 0.0f;
}

template<int LAST>
__global__ __launch_bounds__(NTHR)
void tvl1_fused(float* __restrict__ u,
                float* __restrict__ p1, float* __restrict__ p2,
                const float* __restrict__ gx, const float* __restrict__ gy,
                const float* __restrict__ rc,
                const float* __restrict__ lam, const float* __restrict__ tau,
                const float* __restrict__ the) {
    __shared__ float su0[EXT][EPAD], su1[EXT][EPAD];
    __shared__ float sp10[EXT][EPAD], sp11[EXT][EPAD];
    __shared__ float sp20[EXT][EPAD], sp21[EXT][EPAD];
    __shared__ float sgx[EXT][EPAD], sgy[EXT][EPAD], src_[EXT][EPAD];

    const int tid = threadIdx.x;
    const int b = blockIdx.z;
    const int ox = blockIdx.x*TILE - HALO;
    const int oy = blockIdx.y*TILE - HALO;
    const int pb = b*2*HW, cb = b*HW;
    const float theta = the[0];
    const float tl = theta * lam[0];
    const float r = tau[0] / theta;

    // ---- static px <-> thread mapping (compile-time divisor 48) ----
    int lys[NPX], lxs[NPX];
    bool img[NPX], act[NPX];
    #pragma unroll
    for (int k = 0; k < NPX; ++k) {
        int i = tid + k*NTHR;
        act[k] = (i < EXT*EXT);
        int ii = act[k] ? i : 0;
        int ly = ii / EXT, lx = ii - ly*EXT;
        lys[k] = ly; lxs[k] = lx;
        img[k] = ((unsigned)(oy+ly) < HH) && ((unsigned)(ox+lx) < WW);
    }

    // ---- stage extended tile (zeros outside image) ----
    #pragma unroll
    for (int k = 0; k < NPX; ++k) {
        if (act[k]) {
            int ly = lys[k], lx = lxs[k];
            bool in = img[k];
            int gi = (oy+ly)*WW + (ox+lx);
            su0[ly][lx]  = in ? u[pb + gi]       : 0.0f;
            su1[ly][lx]  = in ? u[pb + HW + gi]  : 0.0f;
            sp10[ly][lx] = in ? p1[pb + gi]      : 0.0f;
            sp11[ly][lx] = in ? p1[pb + HW + gi] : 0.0f;
            sp20[ly][lx] = in ? p2[pb + gi]      : 0.0f;
            sp21[ly][lx] = in ? p2[pb + HW + gi] : 0.0f;
            sgx[ly][lx]  = in ? gx[cb + gi]      : 0.0f;
            sgy[ly][lx]  = in ? gy[cb + gi]      : 0.0f;
            src_[ly][lx] = in ? rc[cb + gi]      : 0.0f;
        }
    }
    __syncthreads();

    const int NH = LAST ? (2*FUSE - 1) : (2*FUSE);
    for (int h = 0; h < NH; ++h) {
        const int lo = h + 1, hi = EXT - 1 - h;
        if ((h & 1) == 0) {
            // ---- u half-step: pointwise in u, reads p neighbors (p frozen) ----
            #pragma unroll
            for (int k = 0; k < NPX; ++k) {
                int ly = lys[k], lx = lxs[k];
                if (act[k] && ly >= lo && ly < hi && lx >= lo && lx < hi) {
                    float g_x = sgx[ly][lx], g_y = sgy[ly][lx];
                    float ng  = g_x*g_x + g_y*g_y + EPSV;
                    float u0  = su0[ly][lx], u1v = su1[ly][lx];
                    float rho = src_[ly][lx] + g_x*u0 + g_y*u1v;
                    float th  = tl * ng;
                    float sgn = (rho > 0.0f) ? 1.0f : ((rho < 0.0f) ? -1.0f : 0.0f);
                    float d   = (fabsf(rho) < th) ? (rho / ng) : (tl * sgn);
                    float div0 = SBX(sp10, ly, lx) + SBY(sp20, ly, lx);
                    float div1 = SBX(sp11, ly, lx) + SBY(sp21, ly, lx);
                    su0[ly][lx] = img[k] ? (u0  - d*g_x + theta*div0) : 0.0f;
                    su1[ly][lx] = img[k] ? (u1v - d*g_y + theta*div1) : 0.0f;
                }
            }
        } else {
            // ---- p half-step: pointwise in p, reads u neighbors (u frozen) ----
            #pragma unroll
            for (int k = 0; k < NPX; ++k) {
                int ly = lys[k], lx = lxs[k];
                if (act[k] && ly >= lo && ly < hi && lx >= lo && lx < hi) {
                    float g1x = SBX(su0, ly, lx), g1y = SBY(su0, ly, lx);
                    float g2x = SBX(su1, ly, lx), g2y = SBY(su1, ly, lx);
                    float inv1 = 1.0f / (1.0f + r*(fabsf(g1x) + fabsf(g1y)));
                    float inv2 = 1.0f / (1.0f + r*(fabsf(g2x) + fabsf(g2y)));
                    sp10[ly][lx] = img[k] ? (sp10[ly][lx] + r*g1x) * inv1 : 0.0f;
                    sp11[ly][lx] = img[k] ? (sp11[ly][lx] + r*g1y) * inv1 : 0.0f;
                    sp20[ly][lx] = img[k] ? (sp20[ly][lx] + r*g2x) * inv2 : 0.0f;
                    sp21[ly][lx] = img[k] ? (sp21[ly][lx] + r*g2y) * inv2 : 0.0f;
                }
            }
        }
        __syncthreads();
    }

    // ---- write back interior (1024 px = 1 px/thread) ----
    {
        int ly = HALO + (tid >> 5), lx = HALO + (tid & 31);
        int gi = (oy + ly)*WW + (ox + lx);   // interior always in-image
        u[pb + gi]      = su0[ly][lx];
        u[pb + HW + gi] = su1[ly][lx];
        if (!LAST) {
            p1[pb + gi]      = sp10[ly][lx];
            p1[pb + HW + gi] = sp11[ly][lx];
            p2[pb + gi]      = sp20[ly][lx];
            p2[pb + HW + gi] = sp21[ly][lx];
        }
    }
}

extern "C" void kernel_launch(void* const* d_in, const int* in_sizes, int n_in,
                              void* d_out, int out_size, void* d_ws, size_t ws_size,
                              hipStream_t stream) {
    const float* xin = (const float*)d_in[0];
    const float* lam = (const float*)d_in[1];
    const float* tau = (const float*)d_in[2];
    const float* the = (const float*)d_in[3];
    float* u = (float*)d_out;              // u lives in d_out (B,2,H,W)

    float* ws = (float*)d_ws;
    float* p1 = ws;                        // B*2*HW
    float* p2 = ws + (size_t)BB*2*HW;      // B*2*HW
    float* gx = ws + (size_t)2*BB*2*HW;    // B*HW
    float* gy = gx + (size_t)BB*HW;        // B*HW
    float* rc = gy + (size_t)BB*HW;        // B*HW

    {
        dim3 blk(64, 4, 1);
        dim3 grd(WW/64, HH/4, BB);
        tvl1_init<<<grd, blk, 0, stream>>>(xin, u, p1, p2, gx, gy, rc);
    }

    dim3 blk(NTHR, 1, 1);
    dim3 grd(WW/TILE, HH/TILE, BB);        // 8 x 8 x 4 = 256 blocks
    const int NLAUNCH = N_ITER / FUSE;     // 5
    for (int j = 0; j < NLAUNCH; ++j) {
        if (j < NLAUNCH - 1)
            tvl1_fused<0><<<grd, blk, 0, stream>>>(u, p1, p2, gx, gy, rc, lam, tau, the);
        else
            tvl1_fused<1><<<grd, blk, 0, stream>>>(u, p1, p2, gx, gy, rc, lam, tau, the);
    }
}